// Round 1
// baseline (349.168 us; speedup 1.0000x reference)
//
#include <hip/hip_runtime.h>
#include <cstdint>

// MoE: B=16384 rows, D=2048 feat, E=16 experts, C=64 classes/expert.
// All math fp32 (argmax outputs can't tolerate bf16 error vs np reference).
// R4: the expert GEMM was LDS-b128-throughput-bound (1.0 B LDS/flop ~= 52 TB/s
// ceiling ~= the measured 53 TF). Restructure: wave-uniform column groups so
// W is read via scalar loads (s_load) from a pre-transposed copy (ewT/cwT) --
// no wT in LDS at all; feature tile stays in LDS ([KCH][TR+1] padded, b32
// reads, zero swizzle math). Accumulate in float2 so the backend emits
// v_pk_fma_f32 (2 FMA/issue). Denser grids: expert TR=128/SK=8 (~1150 blocks),
// coarse TR=256/SK=16 (1024 blocks).
typedef float v2f __attribute__((ext_vector_type(2)));

static constexpr int B_ = 16384;
static constexpr int D_ = 2048;
static constexpr int E_ = 16;
static constexpr int C_ = 64;
static constexpr int KCH = 32;      // K-chunk staged in LDS

static constexpr int TR_E = 128;    // expert tile rows
static constexpr int TR_C = 256;    // coarse tile rows
static constexpr int SK_E_HI = 8;   // expert split-K (big-ws config)
static constexpr int SK_C_HI = 16;  // coarse split-K (big-ws config)
static constexpr int SK_E_LO = 4;   // fallback if workspace is small
static constexpr int SK_C_LO = 8;
static constexpr int MAXITEMS = (B_ / TR_E) + E_;  // 144 worst case

// One-shot W transposes: ewT[e][d][c] = ew[e][c][d]; cwT[d][e] = cw[e][d].
// Makes the per-dd B-operand (consecutive cols at fixed d) contiguous so the
// GEMM can fetch it with wave-uniform scalar loads.
__global__ __launch_bounds__(256) void transpose_w(
    const float* __restrict__ ew, const float* __restrict__ cw,
    float* __restrict__ ewT, float* __restrict__ cwT) {
  const int bid = blockIdx.x;
  const int tid = threadIdx.x;
  if (bid < 128) {                       // ewT: one (e,d) pair per thread
    const int g = bid * 256 + tid;       // 0..32767
    const int eidx = g >> 11;            // g / D_
    const int d = g & (D_ - 1);
    const float* src = ew + ((size_t)eidx * C_) * D_ + d;
    float* dst = ewT + ((size_t)eidx * D_ + d) * C_;
#pragma unroll
    for (int cc = 0; cc < C_; cc += 16) {
      float t[16];
#pragma unroll
      for (int c = 0; c < 16; ++c) t[c] = src[(size_t)(cc + c) * D_];
#pragma unroll
      for (int q = 0; q < 4; ++q)
        *(float4*)(dst + cc + q * 4) =
            make_float4(t[q * 4 + 0], t[q * 4 + 1], t[q * 4 + 2], t[q * 4 + 3]);
    }
  } else {                               // cwT: one d per thread
    const int d = (bid - 128) * 256 + tid;  // 0..2047
    float t[E_];
#pragma unroll
    for (int e2 = 0; e2 < E_; ++e2) t[e2] = cw[(size_t)e2 * D_ + d];
    float* dst = cwT + (size_t)d * E_;
#pragma unroll
    for (int q = 0; q < 4; ++q)
      *(float4*)(dst + q * 4) =
          make_float4(t[q * 4 + 0], t[q * 4 + 1], t[q * 4 + 2], t[q * 4 + 3]);
  }
}

// part[kz][row][c] = sum_{d in kz range} feat[grow][d] * W[c][d].
// Wt is the TRANSPOSED weight [.. d ..][NC] so B-fetches are contiguous.
// Wave w owns cols [w*CW, (w+1)*CW); lanes own rows lane + 64*r (r<RPT).
// B-values are wave-uniform -> scalar loads; A comes from a padded LDS tile
// fT[KCH][TR+1] via conflict-free ds_read_b32 with immediate offsets.
// FLAT mode: dense worker ids from device-built (e,tile) list.
template <int RPT, int CW, int NC, int TR, int SK, bool FLAT>
__global__ __launch_bounds__(256) void gemm_tile(
    const float* __restrict__ feat, const float* __restrict__ Wt,
    const int* __restrict__ rowList, const int* __restrict__ cnt,
    const int* __restrict__ sched, const int* __restrict__ nItems,
    float* __restrict__ part0,      // kz==0 slice (aliased onto d_out region)
    float* __restrict__ partRest)   // kz>=1 slices in ws
{
  constexpr int TRP = TR + 1;             // +1 pad: conflict-free b32 r/w
  constexpr int FITER = TR / 32;          // feature float4 loads/thread/chunk
  static_assert(64 * RPT == TR, "lanes*RPT must cover tile rows");
  static_assert(4 * CW == NC, "4 waves * CW must cover tile cols");

  __shared__ float fT[KCH * TRP];
  __shared__ int rIdx[TR];

  const int tid = threadIdx.x;
  int e, tile, kz;
  if (FLAT) {
    const int b = blockIdx.x;
    kz = b % SK;
    const int item = b / SK;
    if (item >= *nItems) return;  // dense tail exit only (uniform per block)
    const int s = sched[item];
    e = s & 255;
    tile = s >> 8;
  } else {
    e = 0;
    tile = blockIdx.x;
    kz = blockIdx.z;
  }
  // Force scalar-ness so W addressing stays in SGPRs (s_load path).
  e = __builtin_amdgcn_readfirstlane(e);
  tile = __builtin_amdgcn_readfirstlane(tile);
  kz = __builtin_amdgcn_readfirstlane(kz);
  const int count = cnt ? cnt[e] : B_;

  if (tid < TR) {
    const int slot = tile * TR + tid;
    rIdx[tid] = (slot < count) ? (rowList ? rowList[e * B_ + slot] : slot) : 0;
  }
  __syncthreads();

  // loop-invariant staging constants -> registers
  unsigned grows[FITER];
  int dcf[FITER], rls[FITER];
#pragma unroll
  for (int i = 0; i < FITER; ++i) {
    const int idx = i * 256 + tid;
    rls[i] = idx >> 3;
    dcf[i] = idx & 7;
    grows[i] = (unsigned)rIdx[rls[i]];
  }

  const int lane = tid & 63;
  const int w = __builtin_amdgcn_readfirstlane(tid >> 6);
  const int wcol = w * CW;

  v2f acc[RPT][CW / 2];
#pragma unroll
  for (int r = 0; r < RPT; ++r)
#pragma unroll
    for (int j = 0; j < CW / 2; ++j) acc[r][j] = (v2f){0.f, 0.f};

  constexpr int KRANGE = D_ / SK;
  constexpr int NCH = KRANGE / KCH;
  const int k0 = kz * KRANGE;
  const float* Wb = Wt + (size_t)e * D_ * NC;  // Wt[e][d][c] (e=0 for coarse)

  // prefetch chunk 0 into registers
  float4 pf[FITER];
#pragma unroll
  for (int i = 0; i < FITER; ++i)
    pf[i] = *(const float4*)(feat + (size_t)grows[i] * D_ + k0 + dcf[i] * 4);

  for (int ch = 0; ch < NCH; ++ch) {
    // drain prefetch regs -> LDS (padded layout, conflict-free b32 stores)
#pragma unroll
    for (int i = 0; i < FITER; ++i) {
      float* p = &fT[(dcf[i] * 4) * TRP + rls[i]];
      p[0 * TRP] = pf[i].x;
      p[1 * TRP] = pf[i].y;
      p[2 * TRP] = pf[i].z;
      p[3 * TRP] = pf[i].w;
    }
    __syncthreads();
    // issue next chunk's global loads early; they overlap the dd-loop
    if (ch + 1 < NCH) {
      const int kb = k0 + (ch + 1) * KCH;
#pragma unroll
      for (int i = 0; i < FITER; ++i)
        pf[i] = *(const float4*)(feat + (size_t)grows[i] * D_ + kb + dcf[i] * 4);
    }
    const float* wrow = Wb + (size_t)(k0 + ch * KCH) * NC + wcol;
#pragma unroll
    for (int dd = 0; dd < KCH; ++dd) {
      // B: wave-uniform contiguous cols -> s_load pairs (SGPR operands)
      v2f b2[CW / 2];
      const v2f* wp = (const v2f*)(wrow + (size_t)dd * NC);
#pragma unroll
      for (int j = 0; j < CW / 2; ++j) b2[j] = wp[j];
      // A: per-lane rows, immediate-offset ds_read_b32
      float a[RPT];
#pragma unroll
      for (int r = 0; r < RPT; ++r) a[r] = fT[dd * TRP + lane + 64 * r];
#pragma unroll
      for (int r = 0; r < RPT; ++r) {
        const v2f ar = {a[r], a[r]};
#pragma unroll
        for (int j = 0; j < CW / 2; ++j) acc[r][j] += ar * b2[j];  // v_pk_fma
      }
    }
    __syncthreads();
  }

  // epilogue: plain vector stores to this kz's partial slice
  float* pk = kz ? (partRest + (size_t)(kz - 1) * B_ * NC) : part0;
#pragma unroll
  for (int r = 0; r < RPT; ++r) {
    const int lrow = lane + 64 * r;
    const int slot = tile * TR + lrow;
    if (slot < count) {
      const int grow = rIdx[lrow];
      float* dst = pk + (size_t)grow * NC + wcol;
#pragma unroll
      for (int j4 = 0; j4 < CW / 4; ++j4)
        *(float4*)(dst + j4 * 4) =
            make_float4(acc[r][j4 * 2][0], acc[r][j4 * 2][1],
                        acc[r][j4 * 2 + 1][0], acc[r][j4 * 2 + 1][1]);
    }
  }
}

// Reduce coarse partials (fixed order => deterministic), add bias, argmax,
// write coarse_output + expert_id, build compacted row lists (block-aggregated
// atomics: 16 global atomics per block).
template <int SK>
__global__ __launch_bounds__(256) void coarse_finish(
    const float* __restrict__ cpart0, const float* __restrict__ cpartRest,
    const float* __restrict__ cb, float* __restrict__ out0,
    float* __restrict__ out1, int* __restrict__ eidArr, int* __restrict__ cnt,
    int* __restrict__ rowList) {
  __shared__ int lcnt[E_];
  __shared__ int lbase[E_];
  const int tid = threadIdx.x;
  if (tid < E_) lcnt[tid] = 0;
  __syncthreads();
  const int row = blockIdx.x * 256 + tid;

  float v[E_];
#pragma unroll
  for (int j = 0; j < E_; ++j) v[j] = cb[j];
#pragma unroll
  for (int kz = 0; kz < SK; ++kz) {
    const float* p = (kz == 0) ? (cpart0 + (size_t)row * E_)
                               : (cpartRest + ((size_t)(kz - 1) * B_ + row) * E_);
#pragma unroll
    for (int j4 = 0; j4 < E_ / 4; ++j4) {
      const float4 t = *(const float4*)(p + j4 * 4);
      v[j4 * 4 + 0] += t.x;
      v[j4 * 4 + 1] += t.y;
      v[j4 * 4 + 2] += t.z;
      v[j4 * 4 + 3] += t.w;
    }
  }
  int best = 0;
  float bv = v[0];
#pragma unroll
  for (int j = 1; j < E_; ++j)
    if (v[j] > bv) { bv = v[j]; best = j; }

  float* o0 = out0 + (size_t)row * E_;
#pragma unroll
  for (int j4 = 0; j4 < E_ / 4; ++j4)
    *(float4*)(o0 + j4 * 4) = make_float4(v[j4 * 4 + 0], v[j4 * 4 + 1],
                                          v[j4 * 4 + 2], v[j4 * 4 + 3]);
  out1[row] = (float)best;
  eidArr[row] = best;

  const int lpos = atomicAdd(&lcnt[best], 1);
  __syncthreads();
  if (tid < E_) lbase[tid] = atomicAdd(&cnt[tid], lcnt[tid]);
  __syncthreads();
  rowList[best * B_ + lbase[best] + lpos] = row;
}

// Build the dense (e, tile) worker list for the expert GEMM (parallel).
__global__ void make_schedule(const int* __restrict__ cnt,
                              int* __restrict__ sched,
                              int* __restrict__ nItems) {
  __shared__ int tiles[E_];
  __shared__ int offs[E_];
  const int t = threadIdx.x;
  if (t < E_) tiles[t] = (cnt[t] + TR_E - 1) / TR_E;
  __syncthreads();
  if (t == 0) {
    int acc = 0;
    for (int e = 0; e < E_; ++e) {
      offs[e] = acc;
      acc += tiles[e];
    }
    *nItems = acc;
  }
  __syncthreads();
  if (t < E_) {
    const int o = offs[t], n = tiles[t];
    for (int k = 0; k < n; ++k) sched[o + k] = t | (k << 8);
  }
}

// Wave-per-row (C=64 == wave): reduce y partials (fixed order), add bias,
// softmax -> local_preds, first-occurrence argmax + expert class start.
template <int SK>
__global__ __launch_bounds__(256) void finish_rows(
    const float* __restrict__ ypart0, const float* __restrict__ ypartRest,
    const float* __restrict__ eb, const int* __restrict__ eidArr,
    float* __restrict__ out2, float* __restrict__ out3) {
  const int lane = threadIdx.x & 63;
  const int row = (blockIdx.x * 256 + threadIdx.x) >> 6;
  const int eid = eidArr[row];

  float v = eb[eid * C_ + lane];
  v += ypart0[(size_t)row * C_ + lane];
#pragma unroll
  for (int kz = 1; kz < SK; ++kz)
    v += ypartRest[((size_t)(kz - 1) * B_ + row) * C_ + lane];

  float m = v;
#pragma unroll
  for (int off = 32; off; off >>= 1) m = fmaxf(m, __shfl_xor(m, off, 64));
  const float p = __expf(v - m);
  float s = p;
#pragma unroll
  for (int off = 32; off; off >>= 1) s += __shfl_xor(s, off, 64);
  out2[(size_t)row * C_ + lane] = p / s;  // ypart0 aliases out2; read done

  float av = v;
  int ai = lane;
#pragma unroll
  for (int off = 32; off; off >>= 1) {
    const float ov = __shfl_xor(av, off, 64);
    const int oi = __shfl_xor(ai, off, 64);
    if (ov > av || (ov == av && oi < ai)) { av = ov; ai = oi; }
  }
  if (lane == 0) out3[row] = (float)(ai + (eid << 6));
}

extern "C" void kernel_launch(void* const* d_in, const int* in_sizes, int n_in,
                              void* d_out, int out_size, void* d_ws,
                              size_t ws_size, hipStream_t stream) {
  const float* feat = (const float*)d_in[0];  // [B, D]
  const float* cw = (const float*)d_in[1];    // [E, D]
  const float* cb = (const float*)d_in[2];    // [E]
  const float* ew = (const float*)d_in[3];    // [E, C, D]
  const float* eb = (const float*)d_in[4];    // [E, C]

  float* out0 = (float*)d_out;           // coarse_output [B, E]
  float* out1 = out0 + (size_t)B_ * E_;  // expert_id [B] (as float)
  float* out2 = out1 + B_;               // local_preds [B, C]
  float* out3 = out2 + (size_t)B_ * C_;  // global_preds [B]

  // HI config needs ~54.7 MB of ws; fall back to smaller split-K otherwise.
  const bool HI = ws_size >= (size_t)56 * 1024 * 1024;
  const int skC = HI ? SK_C_HI : SK_C_LO;
  const int skE = HI ? SK_E_HI : SK_E_LO;

  // ws layout: W transposes + kz>=1 partial slices + routing metadata.
  // kz==0 slices alias the output regions (same element, same reducing thread).
  char* p = (char*)d_ws;
  float* cwT = (float*)p;            p += (size_t)D_ * E_ * 4;        // [D][E]
  float* ewT = (float*)p;            p += (size_t)E_ * D_ * C_ * 4;   // [E][D][C]
  float* cpartRest = (float*)p;      p += (size_t)(skC - 1) * B_ * E_ * 4;
  float* ypartRest = (float*)p;      p += (size_t)(skE - 1) * B_ * C_ * 4;
  int* rowList = (int*)p;            p += (size_t)E_ * B_ * 4;
  int* cnt = (int*)p;                p += 64 * 4;
  int* eidArr = (int*)p;             p += (size_t)B_ * 4;
  int* sched = (int*)p;              p += 512 * 4;
  int* nItems = (int*)p;

  hipMemsetAsync(cnt, 0, E_ * sizeof(int), stream);

  // 0) transpose W (17 MB of traffic, ~4 us); must precede the GEMMs.
  transpose_w<<<136, 256, 0, stream>>>(ew, cw, ewT, cwT);

  if (HI) {
    // 1) coarse GEMM: grid (64,1,16) = 1024 blocks (~4/CU)
    gemm_tile<4, 4, E_, TR_C, SK_C_HI, false>
        <<<dim3(B_ / TR_C, 1, SK_C_HI), 256, 0, stream>>>(
            feat, cwT, nullptr, nullptr, nullptr, nullptr, out0, cpartRest);
    // 2) reduce + argmax + compaction
    coarse_finish<SK_C_HI><<<B_ / 256, 256, 0, stream>>>(
        out0, cpartRest, cb, out0, out1, eidArr, cnt, rowList);
    // 3) flat schedule, then expert GEMM over a dense 1-D worker grid
    make_schedule<<<1, 64, 0, stream>>>(cnt, sched, nItems);
    gemm_tile<2, 16, C_, TR_E, SK_E_HI, true>
        <<<MAXITEMS * SK_E_HI, 256, 0, stream>>>(feat, ewT, rowList, cnt,
                                                 sched, nItems, out2, ypartRest);
    // 4) softmax + argmax + class-range start
    finish_rows<SK_E_HI><<<(B_ * 64) / 256, 256, 0, stream>>>(
        out2, ypartRest, eb, eidArr, out2, out3);
  } else {
    gemm_tile<4, 4, E_, TR_C, SK_C_LO, false>
        <<<dim3(B_ / TR_C, 1, SK_C_LO), 256, 0, stream>>>(
            feat, cwT, nullptr, nullptr, nullptr, nullptr, out0, cpartRest);
    coarse_finish<SK_C_LO><<<B_ / 256, 256, 0, stream>>>(
        out0, cpartRest, cb, out0, out1, eidArr, cnt, rowList);
    make_schedule<<<1, 64, 0, stream>>>(cnt, sched, nItems);
    gemm_tile<2, 16, C_, TR_E, SK_E_LO, true>
        <<<MAXITEMS * SK_E_LO, 256, 0, stream>>>(feat, ewT, rowList, cnt,
                                                 sched, nItems, out2, ypartRest);
    finish_rows<SK_E_LO><<<(B_ * 64) / 256, 256, 0, stream>>>(
        out2, ypartRest, eb, eidArr, out2, out3);
  }
}

// Round 2
// 301.984 us; speedup vs baseline: 1.1562x; 1.1562x over previous
//
#include <hip/hip_runtime.h>
#include <cstdint>

// MoE: B=16384 rows, D=2048 feat, E=16 experts, C=64 classes/expert.
// All math fp32 (argmax outputs can't tolerate bf16 error vs np reference).
// R5: revert R4's scalar-load W path (s_load+ds_read share lgkmcnt -> forced
// lgkmcnt(0) per dd -> latency-serialized, 91us & VALUBusy 34%). Back to the
// proven R3 structure (298us) and attack the ACTUAL counter signature:
// Occupancy 29% / VALUBusy 45% / HBM 14% == latency-bound from ~4 blocks/CU.
// Double grid density via split-K: SK_E 4->8 (~2176 blocks, ~8.5/CU; LDS cap
// is 9), SK_C 8->16 (2048 blocks). Costs +24MB of partial round-trip (~6us),
// buys ~2x wave-level latency hiding in both GEMMs.
static constexpr int B_ = 16384;
static constexpr int D_ = 2048;
static constexpr int E_ = 16;
static constexpr int C_ = 64;
static constexpr int KCH = 32;     // K-chunk staged in LDS
static constexpr int TR_E = 64;    // expert tile rows
static constexpr int TR_C = 128;   // coarse tile rows
static constexpr int SK_E_HI = 8;  // expert split-K (needs ~46MB ws)
static constexpr int SK_C_HI = 16; // coarse split-K
static constexpr int SK_E_LO = 4;  // fallback config (~21MB ws)
static constexpr int SK_C_LO = 8;
static constexpr int MAXITEMS = (B_ / TR_E) + E_;  // 272 worst case

// part[kz][row][c] = sum_{d in kz range} feat[grow][d]*W[c][d].  W: [NC][D_].
// Feature tile transposed in LDS [dd][row] with XOR swizzle (<=2-way bank
// aliasing, free per m136). FLAT mode: dense worker ids from device-built
// (e,tile) list so active blocks spread over all CUs.
template <int RPT, int CPT, int NC, int TR, int SK, bool FLAT>
__global__ __launch_bounds__(256) void gemm_tile(
    const float* __restrict__ feat, const float* __restrict__ Wall,
    const int* __restrict__ rowList, const int* __restrict__ cnt,
    const int* __restrict__ sched, const int* __restrict__ nItems,
    float* __restrict__ part0,      // kz==0 slice (aliased onto d_out region)
    float* __restrict__ partRest)   // kz>=1 slices in ws
{
  constexpr int FITER = TR / 32;          // feature float4 loads/thread/chunk
  constexpr int WSLOTS = NC * 8;          // weight float4 slots/chunk
  constexpr int WITER = (WSLOTS + 255) / 256;
  constexpr int CG = NC / CPT;

  __shared__ float fT[KCH * TR];
  __shared__ float wT[KCH * NC];
  __shared__ int rIdx[TR];

  const int tid = threadIdx.x;
  int e, tile, kz;
  if (FLAT) {
    const int b = blockIdx.x;
    kz = b % SK;
    const int item = b / SK;
    if (item >= *nItems) return;  // dense tail exit only
    const int s = sched[item];
    e = s & 255;
    tile = s >> 8;
  } else {
    e = 0;
    tile = blockIdx.x;
    kz = blockIdx.z;
  }
  const int count = cnt ? cnt[e] : B_;

  if (tid < TR) {
    const int slot = tile * TR + tid;
    rIdx[tid] = (slot < count) ? (rowList ? rowList[e * B_ + slot] : slot) : 0;
  }
  __syncthreads();

  // loop-invariant staging constants -> registers
  unsigned grows[FITER];
  int dcf[FITER], sbf[FITER];
#pragma unroll
  for (int i = 0; i < FITER; ++i) {
    const int idx = i * 256 + tid;
    const int rl = idx >> 3;
    dcf[i] = idx & 7;
    grows[i] = (unsigned)rIdx[rl];
    sbf[i] = (((rl >> 3) ^ dcf[i]) << 3) + (rl & 7);
  }
  int wc[WITER], wdc[WITER], wsb[WITER];
  bool wact[WITER];
#pragma unroll
  for (int i = 0; i < WITER; ++i) {
    const int idx = i * 256 + tid;
    wact[i] = idx < WSLOTS;
    const int c = (idx < WSLOTS) ? (idx >> 3) : 0;
    wc[i] = c;
    wdc[i] = idx & 7;
    wsb[i] = (((c >> 3) ^ (wdc[i] & (NC / 8 - 1))) << 3) + (c & 7);
  }

  const int cg = tid % CG;
  const int rg = tid / CG;

  float acc[RPT][CPT];
#pragma unroll
  for (int r = 0; r < RPT; ++r)
#pragma unroll
    for (int c = 0; c < CPT; ++c) acc[r][c] = 0.f;

  const float* We = Wall + (size_t)e * NC * D_;
  constexpr int KRANGE = D_ / SK;
  constexpr int NCH = KRANGE / KCH;
  const int k0 = kz * KRANGE;

  // prefetch chunk 0 into registers
  float4 pf[FITER], pw[WITER];
#pragma unroll
  for (int i = 0; i < FITER; ++i)
    pf[i] = *(const float4*)(feat + (size_t)grows[i] * D_ + k0 + dcf[i] * 4);
#pragma unroll
  for (int i = 0; i < WITER; ++i)
    if (wact[i])
      pw[i] = *(const float4*)(We + (size_t)wc[i] * D_ + k0 + wdc[i] * 4);

  for (int ch = 0; ch < NCH; ++ch) {
    // drain prefetch regs -> LDS (transposed + swizzled)
#pragma unroll
    for (int i = 0; i < FITER; ++i) {
      float* p = &fT[(dcf[i] * 4) * TR + sbf[i]];
      p[0 * TR] = pf[i].x;
      p[1 * TR] = pf[i].y;
      p[2 * TR] = pf[i].z;
      p[3 * TR] = pf[i].w;
    }
#pragma unroll
    for (int i = 0; i < WITER; ++i)
      if (wact[i]) {
        float* p = &wT[(wdc[i] * 4) * NC + wsb[i]];
        p[0 * NC] = pw[i].x;
        p[1 * NC] = pw[i].y;
        p[2 * NC] = pw[i].z;
        p[3 * NC] = pw[i].w;
      }
    __syncthreads();
    // issue next chunk's global loads early; they overlap the dd-loop
    if (ch + 1 < NCH) {
      const int kb = k0 + (ch + 1) * KCH;
#pragma unroll
      for (int i = 0; i < FITER; ++i)
        pf[i] = *(const float4*)(feat + (size_t)grows[i] * D_ + kb + dcf[i] * 4);
#pragma unroll
      for (int i = 0; i < WITER; ++i)
        if (wact[i])
          pw[i] = *(const float4*)(We + (size_t)wc[i] * D_ + kb + wdc[i] * 4);
    }
    // outer-product register tile
#pragma unroll
    for (int dd = 0; dd < KCH; ++dd) {
      const int s = dd >> 2;
      const int sw = s & (NC / 8 - 1);
      float a[RPT], bb[CPT];
#pragma unroll
      for (int r4 = 0; r4 < RPT / 4; ++r4) {
        const int col = rg * RPT + r4 * 4;
        const float4 v =
            *(const float4*)&fT[dd * TR + (((col >> 3) ^ s) << 3) + (col & 7)];
        a[r4 * 4 + 0] = v.x;
        a[r4 * 4 + 1] = v.y;
        a[r4 * 4 + 2] = v.z;
        a[r4 * 4 + 3] = v.w;
      }
      if constexpr (CPT >= 4) {
#pragma unroll
        for (int c4 = 0; c4 < CPT / 4; ++c4) {
          const int col = cg * CPT + c4 * 4;
          const float4 v =
              *(const float4*)&wT[dd * NC + (((col >> 3) ^ sw) << 3) + (col & 7)];
          bb[c4 * 4 + 0] = v.x;
          bb[c4 * 4 + 1] = v.y;
          bb[c4 * 4 + 2] = v.z;
          bb[c4 * 4 + 3] = v.w;
        }
      } else {  // CPT == 2
        const int col = cg * 2;
        const float2 v =
            *(const float2*)&wT[dd * NC + (((col >> 3) ^ sw) << 3) + (col & 7)];
        bb[0] = v.x;
        bb[1] = v.y;
      }
#pragma unroll
      for (int r = 0; r < RPT; ++r)
#pragma unroll
        for (int c = 0; c < CPT; ++c) acc[r][c] += a[r] * bb[c];
    }
    __syncthreads();
  }

  // epilogue: plain vector stores to this kz's partial slice
  float* pk = kz ? (partRest + (size_t)(kz - 1) * B_ * NC) : part0;
#pragma unroll
  for (int r = 0; r < RPT; ++r) {
    const int lrow = rg * RPT + r;
    const int slot = tile * TR + lrow;
    if (slot < count) {
      const int grow = rIdx[lrow];
      float* dst = pk + (size_t)grow * NC + cg * CPT;
      if constexpr (CPT >= 4) {
#pragma unroll
        for (int c4 = 0; c4 < CPT / 4; ++c4)
          *(float4*)(dst + c4 * 4) =
              make_float4(acc[r][c4 * 4 + 0], acc[r][c4 * 4 + 1],
                          acc[r][c4 * 4 + 2], acc[r][c4 * 4 + 3]);
      } else {
        *(float2*)dst = make_float2(acc[r][0], acc[r][1]);
      }
    }
  }
}

// Reduce coarse partials (fixed order => deterministic), add bias, argmax,
// write coarse_output + expert_id, build compacted row lists (block-aggregated
// atomics: 16 global atomics per block).
template <int SK>
__global__ __launch_bounds__(256) void coarse_finish(
    const float* __restrict__ cpart0, const float* __restrict__ cpartRest,
    const float* __restrict__ cb, float* __restrict__ out0,
    float* __restrict__ out1, int* __restrict__ eidArr, int* __restrict__ cnt,
    int* __restrict__ rowList) {
  __shared__ int lcnt[E_];
  __shared__ int lbase[E_];
  const int tid = threadIdx.x;
  if (tid < E_) lcnt[tid] = 0;
  __syncthreads();
  const int row = blockIdx.x * 256 + tid;

  float v[E_];
#pragma unroll
  for (int j = 0; j < E_; ++j) v[j] = cb[j];
#pragma unroll
  for (int kz = 0; kz < SK; ++kz) {
    const float* p = (kz == 0) ? (cpart0 + (size_t)row * E_)
                               : (cpartRest + ((size_t)(kz - 1) * B_ + row) * E_);
#pragma unroll
    for (int j4 = 0; j4 < E_ / 4; ++j4) {
      const float4 t = *(const float4*)(p + j4 * 4);
      v[j4 * 4 + 0] += t.x;
      v[j4 * 4 + 1] += t.y;
      v[j4 * 4 + 2] += t.z;
      v[j4 * 4 + 3] += t.w;
    }
  }
  int best = 0;
  float bv = v[0];
#pragma unroll
  for (int j = 1; j < E_; ++j)
    if (v[j] > bv) { bv = v[j]; best = j; }

  float* o0 = out0 + (size_t)row * E_;
#pragma unroll
  for (int j4 = 0; j4 < E_ / 4; ++j4)
    *(float4*)(o0 + j4 * 4) = make_float4(v[j4 * 4 + 0], v[j4 * 4 + 1],
                                          v[j4 * 4 + 2], v[j4 * 4 + 3]);
  out1[row] = (float)best;
  eidArr[row] = best;

  const int lpos = atomicAdd(&lcnt[best], 1);
  __syncthreads();
  if (tid < E_) lbase[tid] = atomicAdd(&cnt[tid], lcnt[tid]);
  __syncthreads();
  rowList[best * B_ + lbase[best] + lpos] = row;
}

// Build the dense (e, tile) worker list for the expert GEMM (parallel).
__global__ void make_schedule(const int* __restrict__ cnt,
                              int* __restrict__ sched,
                              int* __restrict__ nItems) {
  __shared__ int tiles[E_];
  __shared__ int offs[E_];
  const int t = threadIdx.x;
  if (t < E_) tiles[t] = (cnt[t] + TR_E - 1) / TR_E;
  __syncthreads();
  if (t == 0) {
    int acc = 0;
    for (int e = 0; e < E_; ++e) {
      offs[e] = acc;
      acc += tiles[e];
    }
    *nItems = acc;
  }
  __syncthreads();
  if (t < E_) {
    const int o = offs[t], n = tiles[t];
    for (int k = 0; k < n; ++k) sched[o + k] = t | (k << 8);
  }
}

// Wave-per-row (C=64 == wave): reduce y partials (fixed order), add bias,
// softmax -> local_preds, first-occurrence argmax + expert class start.
template <int SK>
__global__ __launch_bounds__(256) void finish_rows(
    const float* __restrict__ ypart0, const float* __restrict__ ypartRest,
    const float* __restrict__ eb, const int* __restrict__ eidArr,
    float* __restrict__ out2, float* __restrict__ out3) {
  const int lane = threadIdx.x & 63;
  const int row = (blockIdx.x * 256 + threadIdx.x) >> 6;
  const int eid = eidArr[row];

  float v = eb[eid * C_ + lane];
  v += ypart0[(size_t)row * C_ + lane];
#pragma unroll
  for (int kz = 1; kz < SK; ++kz)
    v += ypartRest[((size_t)(kz - 1) * B_ + row) * C_ + lane];

  float m = v;
#pragma unroll
  for (int off = 32; off; off >>= 1) m = fmaxf(m, __shfl_xor(m, off, 64));
  const float p = __expf(v - m);
  float s = p;
#pragma unroll
  for (int off = 32; off; off >>= 1) s += __shfl_xor(s, off, 64);
  out2[(size_t)row * C_ + lane] = p / s;  // ypart0 aliases out2; read done

  float av = v;
  int ai = lane;
#pragma unroll
  for (int off = 32; off; off >>= 1) {
    const float ov = __shfl_xor(av, off, 64);
    const int oi = __shfl_xor(ai, off, 64);
    if (ov > av || (ov == av && oi < ai)) { av = ov; ai = oi; }
  }
  if (lane == 0) out3[row] = (float)(ai + (eid << 6));
}

extern "C" void kernel_launch(void* const* d_in, const int* in_sizes, int n_in,
                              void* d_out, int out_size, void* d_ws,
                              size_t ws_size, hipStream_t stream) {
  const float* feat = (const float*)d_in[0];  // [B, D]
  const float* cw = (const float*)d_in[1];    // [E, D]
  const float* cb = (const float*)d_in[2];    // [E]
  const float* ew = (const float*)d_in[3];    // [E, C, D]
  const float* eb = (const float*)d_in[4];    // [E, C]

  float* out0 = (float*)d_out;           // coarse_output [B, E]
  float* out1 = out0 + (size_t)B_ * E_;  // expert_id [B] (as float)
  float* out2 = out1 + B_;               // local_preds [B, C]
  float* out3 = out2 + (size_t)B_ * C_;  // global_preds [B]

  // HI config needs ~46.2 MB of ws; else fall back to the 298us R3 config.
  const bool HI = ws_size >= (size_t)48 * 1024 * 1024;
  const int skC = HI ? SK_C_HI : SK_C_LO;
  const int skE = HI ? SK_E_HI : SK_E_LO;

  // ws layout: kz>=1 partial slices + routing metadata. kz==0 slices alias
  // the output regions (same element written by the same reducing thread).
  char* p = (char*)d_ws;
  float* cpartRest = (float*)p;  p += (size_t)(skC - 1) * B_ * E_ * 4;
  float* ypartRest = (float*)p;  p += (size_t)(skE - 1) * B_ * C_ * 4;
  int* rowList = (int*)p;        p += (size_t)E_ * B_ * 4;
  int* cnt = (int*)p;            p += 64 * 4;
  int* eidArr = (int*)p;         p += (size_t)B_ * 4;
  int* sched = (int*)p;          p += 512 * 4;
  int* nItems = (int*)p;

  hipMemsetAsync(cnt, 0, E_ * sizeof(int), stream);

  if (HI) {
    // 1) coarse GEMM: grid (128,1,16) = 2048 blocks (~8/CU)
    gemm_tile<4, 2, E_, TR_C, SK_C_HI, false>
        <<<dim3(B_ / TR_C, 1, SK_C_HI), 256, 0, stream>>>(
            feat, cw, nullptr, nullptr, nullptr, nullptr, out0, cpartRest);
    // 2) reduce + argmax + compaction
    coarse_finish<SK_C_HI><<<B_ / 256, 256, 0, stream>>>(
        out0, cpartRest, cb, out0, out1, eidArr, cnt, rowList);
    // 3) flat schedule, then expert GEMM over a dense 1-D worker grid
    //    (~272*8 = 2176 blocks, ~8.5/CU; LDS 16.9KB caps at 9/CU)
    make_schedule<<<1, 64, 0, stream>>>(cnt, sched, nItems);
    gemm_tile<4, 4, C_, TR_E, SK_E_HI, true>
        <<<MAXITEMS * SK_E_HI, 256, 0, stream>>>(feat, ew, rowList, cnt,
                                                 sched, nItems, out2, ypartRest);
    // 4) softmax + argmax + class-range start
    finish_rows<SK_E_HI><<<(B_ * 64) / 256, 256, 0, stream>>>(
        out2, ypartRest, eb, eidArr, out2, out3);
  } else {
    gemm_tile<4, 2, E_, TR_C, SK_C_LO, false>
        <<<dim3(B_ / TR_C, 1, SK_C_LO), 256, 0, stream>>>(
            feat, cw, nullptr, nullptr, nullptr, nullptr, out0, cpartRest);
    coarse_finish<SK_C_LO><<<B_ / 256, 256, 0, stream>>>(
        out0, cpartRest, cb, out0, out1, eidArr, cnt, rowList);
    make_schedule<<<1, 64, 0, stream>>>(cnt, sched, nItems);
    gemm_tile<4, 4, C_, TR_E, SK_E_LO, true>
        <<<MAXITEMS * SK_E_LO, 256, 0, stream>>>(feat, ew, rowList, cnt,
                                                 sched, nItems, out2, ypartRest);
    finish_rows<SK_E_LO><<<(B_ * 64) / 256, 256, 0, stream>>>(
        out2, ypartRest, eb, eidArr, out2, out3);
  }
}